// Round 6
// baseline (461.677 us; speedup 1.0000x reference)
//
#include <hip/hip_runtime.h>
#include <hip/hip_bf16.h>
#include <stdint.h>

#define TN 4096
#define TD 2048
#define TMARGIN 0.3f
#define BK 32
#define NT (TD / BK)   // 64 K-tiles

typedef __bf16 bf16x8 __attribute__((ext_vector_type(8)));
typedef float f32x16 __attribute__((ext_vector_type(16)));

// ---------------------------------------------------------------------------
// Kernel 1: per-row prep — fp32 row norm, bf16 hi/lo split, init ap/an.
// ---------------------------------------------------------------------------
__global__ __launch_bounds__(256) void prep_kernel(
    const float* __restrict__ X,
    __bf16* __restrict__ H, __bf16* __restrict__ L,
    float* __restrict__ sq, float* __restrict__ ap, unsigned* __restrict__ an_bits)
{
    const int r = blockIdx.x;
    const int t = threadIdx.x;
    const float* xr = X + (size_t)r * TD;

    float4 v0 = ((const float4*)xr)[t * 2 + 0];
    float4 v1 = ((const float4*)xr)[t * 2 + 1];
    float xs[8] = {v0.x, v0.y, v0.z, v0.w, v1.x, v1.y, v1.z, v1.w};

    bf16x8 hv, lv;
    float s = 0.f;
#pragma unroll
    for (int i = 0; i < 8; ++i) {
        float x = xs[i];
        s += x * x;
        __bf16 h = (__bf16)x;          // RNE
        float res = x - (float)h;      // exact
        hv[i] = h;
        lv[i] = (__bf16)res;
    }
    ((bf16x8*)(H + (size_t)r * TD))[t] = hv;
    ((bf16x8*)(L + (size_t)r * TD))[t] = lv;

#pragma unroll
    for (int off = 32; off; off >>= 1) s += __shfl_down(s, off);
    __shared__ float red[4];
    if ((t & 63) == 0) red[t >> 6] = s;
    __syncthreads();
    if (t == 0) {
        sq[r] = red[0] + red[1] + red[2] + red[3];
        ap[r] = 0.0f;                   // diagonal positive has dist ~0
        an_bits[r] = 0x7f800000u;       // +inf
    }
}

// ---------------------------------------------------------------------------
// Kernel 2: 256x256 tile, 8 waves, 3-pass split-GEMM (hh+hl+lh), 32x32x16
// MFMA (conflict-free LDS reads), carried-MFMA software pipeline:
// lh-pass of tile t issues at top of tile t+1, overlapping the new tile's
// ds_reads. 2 barriers/tile, counted vmcnt(4) (never 0), counted lgkm.
// B-operand ping-pong across 2 physical register slots.
// ---------------------------------------------------------------------------
__device__ __forceinline__ void gload_lds16(const void* g, void* l) {
    __builtin_amdgcn_global_load_lds(
        (const __attribute__((address_space(1))) uint32_t*)g,
        (__attribute__((address_space(3))) uint32_t*)l, 16, 0, 0);
}

#define VMCNT(N) asm volatile("s_waitcnt vmcnt(" #N ")" ::: "memory")
#define LGKM(N)  asm volatile("s_waitcnt lgkmcnt(" #N ")" ::: "memory")
#define BAR()    __builtin_amdgcn_s_barrier()
#define SCHED0() __builtin_amdgcn_sched_barrier(0)

__global__ __launch_bounds__(512, 2) void tile_kernel(
    const __bf16* __restrict__ H, const __bf16* __restrict__ L,
    const float* __restrict__ sq, const int* __restrict__ tg,
    unsigned* __restrict__ ap_bits, unsigned* __restrict__ an_bits)
{
    // 2 dbuf x {0=Ha, 1=La, 2=Hb, 3=Lb} x 256 rows x 32 cols bf16 = 128 KiB
    __shared__ __bf16 lds[2][4][256 * BK];

    const int bi = blockIdx.y, bj = blockIdx.x;
    const int brow = bi * 256, bcol = bj * 256;
    const int tid  = threadIdx.x;
    const int lane = tid & 63;
    const int wave = tid >> 6;
    const int wr = wave >> 2;            // 0..1  (M half)
    const int wc = wave & 3;             // 0..3  (N quarter)
    const int l32 = lane & 31;           // row within 32x32 tile
    const int hi  = lane >> 5;           // k-half selector
    const int sw  = (l32 ^ (l32 >> 2)) & 3;   // read-side XOR swizzle

    // staging: thread covers rows srow and srow+128 of a unit
    const int srow  = tid >> 2;                      // 0..127
    const int sslot = tid & 3;                       // physical 16B slot
    const int rsw   = (srow ^ (srow >> 2)) & 3;
    const int scol0 = (sslot ^ rsw) * 8;             // logical col fetched

    f32x16 acc[4][2];
#pragma unroll
    for (int mt = 0; mt < 4; ++mt)
#pragma unroll
        for (int nt = 0; nt < 2; ++nt)
#pragma unroll
            for (int e = 0; e < 16; ++e)
                acc[mt][nt][e] = 0.f;

    auto stage = [&](const __bf16* __restrict__ src, int rowbase, int d, int u, int k0) {
        const __bf16* g0 = src + (size_t)(rowbase + srow) * TD + (k0 + scol0);
        const __bf16* g1 = src + (size_t)(rowbase + srow + 128) * TD + (k0 + scol0);
        gload_lds16(g0, &lds[d][u][(size_t)tid * 8]);
        gload_lds16(g1, &lds[d][u][(size_t)(tid + 512) * 8]);
    };

    bf16x8 ah[4][2], al[4][2], B0[2][2], B1[2][2];
    // zero-init al and B1 so the t=0 dummy carried-mma adds 0
#pragma unroll
    for (int mt = 0; mt < 4; ++mt)
#pragma unroll
        for (int kst = 0; kst < 2; ++kst)
#pragma unroll
            for (int e = 0; e < 8; ++e) al[mt][kst][e] = (__bf16)0.f;
#pragma unroll
    for (int nt = 0; nt < 2; ++nt)
#pragma unroll
        for (int kst = 0; kst < 2; ++kst)
#pragma unroll
            for (int e = 0; e < 8; ++e) B1[nt][kst][e] = (__bf16)0.f;

    auto readA = [&](int d, int u, bf16x8 (&dst)[4][2]) {
#pragma unroll
        for (int mt = 0; mt < 4; ++mt)
#pragma unroll
            for (int kst = 0; kst < 2; ++kst) {
                int row  = wr * 128 + mt * 32 + l32;
                int slot = (kst * 2 + hi) ^ sw;
                dst[mt][kst] = *(const bf16x8*)&lds[d][u][row * BK + slot * 8];
            }
    };
    auto readB = [&](int d, int u, bf16x8 (&dst)[2][2]) {
#pragma unroll
        for (int nt = 0; nt < 2; ++nt)
#pragma unroll
            for (int kst = 0; kst < 2; ++kst) {
                int row  = wc * 64 + nt * 32 + l32;
                int slot = (kst * 2 + hi) ^ sw;
                dst[nt][kst] = *(const bf16x8*)&lds[d][u][row * BK + slot * 8];
            }
    };
    auto mma16 = [&](bf16x8 (&a)[4][2], bf16x8 (&b)[2][2]) {
        __builtin_amdgcn_s_setprio(1);
#pragma unroll
        for (int mt = 0; mt < 4; ++mt)
#pragma unroll
            for (int nt = 0; nt < 2; ++nt)
#pragma unroll
                for (int kst = 0; kst < 2; ++kst)
                    acc[mt][nt] = __builtin_amdgcn_mfma_f32_32x32x16_bf16(
                        a[mt][kst], b[nt][kst], acc[mt][nt], 0, 0, 0);
        __builtin_amdgcn_s_setprio(0);
    };

    // Prologue: stage tile0's 4 units; vmcnt(4) drains Ha0,Hb0 (FIFO oldest),
    // leaving [Lb0, La0] in flight = the loop entry invariant.
    stage(H, brow, 0, 0, 0);   // Ha(0)
    stage(H, bcol, 0, 2, 0);   // Hb(0)
    stage(L, bcol, 0, 3, 0);   // Lb(0)
    stage(L, brow, 0, 1, 0);   // La(0)
    VMCNT(4);
    BAR();

    // Body: Bc = bh_cur slot, Bp = bh_prev slot (also reused for bl).
    auto body = [&](int t, bf16x8 (&Bc)[2][2], bf16x8 (&Bp)[2][2]) {
        const int d = t & 1, dn = d ^ 1;
        const int k1 = ((t + 1 < NT) ? t + 1 : NT - 1) * BK;

        // ---- first half: units 0 (Ha) and 2 (Hb), drained pre-top-BAR ----
        readA(d, 0, ah);            // 8 ds_reads
        readB(d, 2, Bc);            // 4 ds_reads
        stage(H, brow, dn, 0, k1);  // Ha''  -> vmem queue [Lb',La',Ha'',Hb'']
        stage(H, bcol, dn, 2, k1);
        VMCNT(4);                   // drain Lb',La' (cross-wave via BAR2)
        LGKM(12); SCHED0();         // drain prev-tile al only (in-order retire)
        mma16(al, Bp);              // carried lh of tile t-1 (regs only)
        LGKM(0); SCHED0();
        mma16(ah, Bc);              // hh
        BAR();                      // BAR2: Lb',La' visible to all waves

        // ---- second half: units 3 (Lb) and 1 (La) ----
        readB(d, 3, Bp);            // bl -> reuses Bp slot (prev consumed)
        readA(d, 1, al);            // 8 ds_reads (al streams under mma_hl)
        stage(L, bcol, dn, 3, k1);  // Lb''
        stage(L, brow, dn, 1, k1);  // La''  -> queue [Ha'',Hb'',Lb'',La'']
        LGKM(8); SCHED0();          // drain bl, leave al in flight
        mma16(ah, Bp);              // hl
        VMCNT(4);                   // drain Ha'',Hb'' (cross-wave via top BAR)
        // lh (al x Bc) carried into next tile
        BAR();                      // top BAR of tile t+1
    };

    for (int tt = 0; tt < NT; tt += 2) {
        body(tt,     B0, B1);
        body(tt + 1, B1, B0);
    }
    // final carried lh: last tile (odd) had Bc = B1
    LGKM(0); SCHED0();
    mma16(al, B1);

    // Epilogue: dist + hard mining.
    // C/D 32x32 layout: col = lane&31, row = (reg&3)+8*(reg>>2)+4*(lane>>5)
    float sqj[2]; int tj[2];
#pragma unroll
    for (int nt = 0; nt < 2; ++nt) {
        int j = bcol + wc * 64 + nt * 32 + l32;
        sqj[nt] = sq[j];
        tj[nt]  = tg[j];
    }
#pragma unroll
    for (int mt = 0; mt < 4; ++mt) {
#pragma unroll
        for (int r = 0; r < 16; ++r) {
            int i = brow + wr * 128 + mt * 32 + (r & 3) + 8 * (r >> 2) + 4 * hi;
            float sqi = sq[i];
            int   ti  = tg[i];
            float pmax = -1.0f;
            float pmin = __uint_as_float(0x7f800000u);
#pragma unroll
            for (int nt = 0; nt < 2; ++nt) {
                float d2   = sqi + sqj[nt] - 2.0f * acc[mt][nt][r];
                float dist = sqrtf(fmaxf(d2, 1e-12f));
                if (ti == tj[nt]) pmax = fmaxf(pmax, dist);
                else              pmin = fminf(pmin, dist);
            }
#pragma unroll
            for (int off = 1; off < 32; off <<= 1) {
                pmax = fmaxf(pmax, __shfl_xor(pmax, off));
                pmin = fminf(pmin, __shfl_xor(pmin, off));
            }
            if (l32 == 0) {
                if (pmax >= 0.0f) atomicMax(&ap_bits[i], __float_as_uint(pmax));
                atomicMin(&an_bits[i], __float_as_uint(pmin));
            }
        }
    }
}

// ---------------------------------------------------------------------------
// Kernel 3: loss = mean(relu(ap - an + margin)), prec = mean(an > ap).
// ---------------------------------------------------------------------------
__global__ __launch_bounds__(256) void finalize_kernel(
    const float* __restrict__ ap, const float* __restrict__ an, float* __restrict__ out)
{
    const int t = threadIdx.x;
    float ls = 0.f, ps = 0.f;
    for (int i = t; i < TN; i += 256) {
        float a = ap[i], b = an[i];
        ls += fmaxf(a - b + TMARGIN, 0.f);
        ps += (b > a) ? 1.f : 0.f;
    }
#pragma unroll
    for (int off = 32; off; off >>= 1) {
        ls += __shfl_down(ls, off);
        ps += __shfl_down(ps, off);
    }
    __shared__ float r0[4], r1[4];
    if ((t & 63) == 0) { r0[t >> 6] = ls; r1[t >> 6] = ps; }
    __syncthreads();
    if (t == 0) {
        out[0] = (r0[0] + r0[1] + r0[2] + r0[3]) / (float)TN;
        out[1] = (r1[0] + r1[1] + r1[2] + r1[3]) / (float)TN;
    }
}

// ---------------------------------------------------------------------------
extern "C" void kernel_launch(void* const* d_in, const int* in_sizes, int n_in,
                              void* d_out, int out_size, void* d_ws, size_t ws_size,
                              hipStream_t stream)
{
    const float* X  = (const float*)d_in[0];
    const int*   tg = (const int*)d_in[1];
    float* out = (float*)d_out;

    char* ws = (char*)d_ws;
    __bf16* Hp = (__bf16*)ws;                                   // 16 MB
    __bf16* Lp = (__bf16*)(ws + (size_t)TN * TD * 2);           // 16 MB
    float*  sq = (float*) (ws + (size_t)TN * TD * 4);           // 16 KB
    float*  ap = sq + TN;
    float*  an = ap + TN;

    prep_kernel<<<TN, 256, 0, stream>>>(X, Hp, Lp, sq, ap, (unsigned*)an);

    dim3 grid(4096 / 256, 4096 / 256);   // 16 x 16 = 256 blocks
    tile_kernel<<<grid, 512, 0, stream>>>(Hp, Lp, sq, tg,
                                          (unsigned*)ap, (unsigned*)an);

    finalize_kernel<<<1, 256, 0, stream>>>(ap, an, out);
}

// Round 8
// 175.174 us; speedup vs baseline: 2.6355x; 2.6355x over previous
//
#include <hip/hip_runtime.h>
#include <hip/hip_bf16.h>
#include <stdint.h>

#define TN 4096
#define TD 2048
#define TMARGIN 0.3f
#define BK 64
#define NT (TD / BK)   // 32 K-tiles

typedef _Float16 f16x8 __attribute__((ext_vector_type(8)));
typedef float f32x4 __attribute__((ext_vector_type(4)));

// ---------------------------------------------------------------------------
// Kernel 1: per-row prep — fp32 row norm (from X, as reference), f16 cast,
// init ap/an.
// ---------------------------------------------------------------------------
__global__ __launch_bounds__(256) void prep_kernel(
    const float* __restrict__ X, _Float16* __restrict__ H,
    float* __restrict__ sq, float* __restrict__ ap, unsigned* __restrict__ an_bits)
{
    const int r = blockIdx.x;
    const int t = threadIdx.x;
    const float* xr = X + (size_t)r * TD;

    float4 v0 = ((const float4*)xr)[t * 2 + 0];
    float4 v1 = ((const float4*)xr)[t * 2 + 1];
    float xs[8] = {v0.x, v0.y, v0.z, v0.w, v1.x, v1.y, v1.z, v1.w};

    f16x8 hv;
    float s = 0.f;
#pragma unroll
    for (int i = 0; i < 8; ++i) {
        float x = xs[i];
        s += x * x;
        hv[i] = (_Float16)x;           // RNE
    }
    ((f16x8*)(H + (size_t)r * TD))[t] = hv;

#pragma unroll
    for (int off = 32; off; off >>= 1) s += __shfl_down(s, off);
    __shared__ float red[4];
    if ((t & 63) == 0) red[t >> 6] = s;
    __syncthreads();
    if (t == 0) {
        sq[r] = red[0] + red[1] + red[2] + red[3];
        ap[r] = 0.0f;                   // diagonal positive has dist ~0
        an_bits[r] = 0x7f800000u;       // +inf
    }
}

// ---------------------------------------------------------------------------
// Kernel 2: 256x256 tile, 8 waves, SINGLE-PASS f16 GEMM, BK=64,
// 2 phases/K-tile x 32 MFMA (16x16x32_f16). FIFO-ledgered counted vmcnt
// (never 0), conflict-free XOR-swizzled LDS, fused dist+mining epilogue.
// ---------------------------------------------------------------------------
__device__ __forceinline__ void gload_lds16(const void* g, void* l) {
    __builtin_amdgcn_global_load_lds(
        (const __attribute__((address_space(1))) uint32_t*)g,
        (__attribute__((address_space(3))) uint32_t*)l, 16, 0, 0);
}

#define VMCNT(N) asm volatile("s_waitcnt vmcnt(" #N ")" ::: "memory")
#define LGKM0()  asm volatile("s_waitcnt lgkmcnt(0)" ::: "memory")
#define BAR()    __builtin_amdgcn_s_barrier()
#define SCHED0() __builtin_amdgcn_sched_barrier(0)

__global__ __launch_bounds__(512, 2) void tile_kernel(
    const _Float16* __restrict__ H,
    const float* __restrict__ sq, const int* __restrict__ tg,
    unsigned* __restrict__ ap_bits, unsigned* __restrict__ an_bits)
{
    // A: [dbuf][256 rows x 8 slots x 8 f16] = 2 x 32 KiB
    // B: [dbuf][khalf][256 rows x 4 slots x 8 f16] = 4 x 16 KiB   (total 128 KiB)
    __shared__ _Float16 ldsA[2][256 * 64];
    __shared__ _Float16 ldsB[2][2][256 * 32];

    const int bi = blockIdx.y, bj = blockIdx.x;
    const int brow = bi * 256, bcol = bj * 256;
    const int tid  = threadIdx.x;
    const int lane = tid & 63;
    const int wave = tid >> 6;
    const int wr = wave >> 2;            // 0..1  (M half: rows wr*128..+128)
    const int wc = wave & 3;             // 0..3  (N quarter: cols wc*64..+64)
    const int lr = lane & 15;            // fragment row/col
    const int lk = lane >> 4;            // 0..3 (k-slice)

    f32x4 acc[8][4];
#pragma unroll
    for (int m = 0; m < 8; ++m)
#pragma unroll
        for (int n = 0; n < 4; ++n)
            acc[m][n] = (f32x4){0.f, 0.f, 0.f, 0.f};

    // ---- staging (linear LDS dest per gload rule; source pre-swizzled) ----
    auto stageA = [&](int d, int k0) {      // 4 gloads: full 256x64 A unit
#pragma unroll
        for (int g = 0; g < 4; ++g) {
            int D = tid + g * 512;          // slot index 0..2047
            int r = D >> 3, p = D & 7;
            int l = p ^ (r & 7);            // logical 8-f16 col group
            gload_lds16(H + (size_t)(brow + r) * TD + k0 + l * 8,
                        &ldsA[d][(size_t)D * 8]);
        }
    };
    auto stageB = [&](int d, int kh, int k0) {  // 2 gloads: 256x32 B half
#pragma unroll
        for (int g = 0; g < 2; ++g) {
            int D = tid + g * 512;          // slot index 0..1023
            int r = D >> 2, p = D & 3;
            int l = p ^ (r & 3);
            gload_lds16(H + (size_t)(bcol + r) * TD + k0 + kh * 32 + l * 8,
                        &ldsB[d][kh][(size_t)D * 8]);
        }
    };

    f16x8 ah[8], bh[4];

    auto readA = [&](int d, int kst) {      // 8 ds_read_b128, conflict-free
#pragma unroll
        for (int m = 0; m < 8; ++m) {
            int row  = wr * 128 + m * 16 + lr;
            int phys = (kst * 4 + lk) ^ (row & 7);
            ah[m] = *(const f16x8*)&ldsA[d][row * 64 + phys * 8];
        }
    };
    auto readB = [&](int d, int kst) {      // 4 ds_read_b128
#pragma unroll
        for (int n = 0; n < 4; ++n) {
            int row  = wc * 64 + n * 16 + lr;
            int phys = lk ^ (row & 3);
            bh[n] = *(const f16x8*)&ldsB[d][kst][row * 32 + phys * 8];
        }
    };
    auto mma32 = [&]() {                    // 32 independent MFMAs
        __builtin_amdgcn_s_setprio(1);
#pragma unroll
        for (int m = 0; m < 8; ++m)
#pragma unroll
            for (int n = 0; n < 4; ++n)
                acc[m][n] = __builtin_amdgcn_mfma_f32_16x16x32_f16(
                    ah[m], bh[n], acc[m][n], 0, 0, 0);
        __builtin_amdgcn_s_setprio(0);
    };

    // Prologue: issue A(0)[4], Bk0(0)[2], Bk1(0)[2]; vmcnt(2) drains A+Bk0,
    // leaving [Bk1(0):2] in flight = loop entry invariant.
    stageA(0, 0);
    stageB(0, 0, 0);
    stageB(0, 1, 0);
    VMCNT(2);
    BAR();

    for (int t = 0; t < NT; ++t) {
        const int d = t & 1, dn = d ^ 1;
        const int k1 = ((t + 1 < NT) ? t + 1 : NT - 1) * BK;

        // p0 (kst=0): reads A[.,k0], B[k0] (drained at (t-1).p1 / prologue).
        stageA(dn, k1);                 // issue A'      q: [Bk1(t):2, A':4]
        stageB(dn, 0, k1);              // issue Bk0'    q: +2 = 8
        readA(d, 0);
        readB(d, 0);
        VMCNT(6);                       // drains Bk1(t) (consumed p1)
        BAR(); LGKM0(); SCHED0();
        mma32();
        BAR();

        // p1 (kst=1): reads A[.,k1], B[k1] (Bk1 drained at p0).
        stageB(dn, 1, k1);              // issue Bk1'    q: [A':4,Bk0':2,Bk1':2]=8
        readA(d, 1);
        readB(d, 1);
        VMCNT(2);                       // drains A', Bk0' (consumed (t+1).p0)
        BAR(); LGKM0(); SCHED0();
        mma32();
        BAR();
    }

    // Epilogue: dist = sqrt(clip(sq_i + sq_j - 2*dot)), hard mining.
    // C/D layout (verified R1-R4): col = lane&15, row = lk*4 + reg.
    float sqj[4]; int tj[4];
#pragma unroll
    for (int n = 0; n < 4; ++n) {
        int j = bcol + wc * 64 + n * 16 + lr;
        sqj[n] = sq[j];
        tj[n]  = tg[j];
    }
#pragma unroll
    for (int m = 0; m < 8; ++m) {
#pragma unroll
        for (int reg = 0; reg < 4; ++reg) {
            int i = brow + wr * 128 + m * 16 + lk * 4 + reg;
            float sqi = sq[i];
            int   ti  = tg[i];
            float pmax = -1.0f;
            float pmin = __uint_as_float(0x7f800000u);
#pragma unroll
            for (int n = 0; n < 4; ++n) {
                float d2   = sqi + sqj[n] - 2.0f * acc[m][n][reg];
                float dist = sqrtf(fmaxf(d2, 1e-12f));
                if (ti == tj[n]) pmax = fmaxf(pmax, dist);
                else             pmin = fminf(pmin, dist);
            }
#pragma unroll
            for (int off = 1; off < 16; off <<= 1) {
                pmax = fmaxf(pmax, __shfl_xor(pmax, off));
                pmin = fminf(pmin, __shfl_xor(pmin, off));
            }
            if (lr == 0) {
                if (pmax >= 0.0f) atomicMax(&ap_bits[i], __float_as_uint(pmax));
                atomicMin(&an_bits[i], __float_as_uint(pmin));
            }
        }
    }
}

// ---------------------------------------------------------------------------
// Kernel 3: loss = mean(relu(ap - an + margin)), prec = mean(an > ap).
// ---------------------------------------------------------------------------
__global__ __launch_bounds__(256) void finalize_kernel(
    const float* __restrict__ ap, const float* __restrict__ an, float* __restrict__ out)
{
    const int t = threadIdx.x;
    float ls = 0.f, ps = 0.f;
    for (int i = t; i < TN; i += 256) {
        float a = ap[i], b = an[i];
        ls += fmaxf(a - b + TMARGIN, 0.f);
        ps += (b > a) ? 1.f : 0.f;
    }
#pragma unroll
    for (int off = 32; off; off >>= 1) {
        ls += __shfl_down(ls, off);
        ps += __shfl_down(ps, off);
    }
    __shared__ float r0[4], r1[4];
    if ((t & 63) == 0) { r0[t >> 6] = ls; r1[t >> 6] = ps; }
    __syncthreads();
    if (t == 0) {
        out[0] = (r0[0] + r0[1] + r0[2] + r0[3]) / (float)TN;
        out[1] = (r1[0] + r1[1] + r1[2] + r1[3]) / (float)TN;
    }
}

// ---------------------------------------------------------------------------
extern "C" void kernel_launch(void* const* d_in, const int* in_sizes, int n_in,
                              void* d_out, int out_size, void* d_ws, size_t ws_size,
                              hipStream_t stream)
{
    const float* X  = (const float*)d_in[0];
    const int*   tg = (const int*)d_in[1];
    float* out = (float*)d_out;

    char* ws = (char*)d_ws;
    _Float16* Hp = (_Float16*)ws;                               // 16 MB
    float*    sq = (float*)(ws + (size_t)TN * TD * 2);          // 16 KB
    float*    ap = sq + TN;
    float*    an = ap + TN;

    prep_kernel<<<TN, 256, 0, stream>>>(X, Hp, sq, ap, (unsigned*)an);

    dim3 grid(4096 / 256, 4096 / 256);   // 16 x 16 = 256 blocks
    tile_kernel<<<grid, 512, 0, stream>>>(Hp, sq, tg,
                                          (unsigned*)ap, (unsigned*)an);

    finalize_kernel<<<1, 256, 0, stream>>>(ap, an, out);
}